// Round 3
// baseline (2671.768 us; speedup 1.0000x reference)
//
#include <hip/hip_runtime.h>
#include <hip/hip_bf16.h>
#include <math.h>

#define WINS 16
#define LTOK 256      // window length L = 16*16
#define CCH  512
#define NH   16
#define DH   32
#define NBW  256
#define LOG_MAX_F 4.605170185988092f
#define EPS_F 1e-12f

// ---------------------------------------------------------------------------
// Kernel 1: relative-position-bias MLP table, layout (H=16, 961) so each
// head's slice is contiguous (L1-resident in the attention kernel).
// table[h][e] = sum_j fc2_w[h][j]*relu(fc1_w[j][0]*rx + fc1_w[j][1]*ry + fc1_b[j]) + fc2_b[h]
// ---------------------------------------------------------------------------
__global__ __launch_bounds__(64) void bias_mlp_kernel(
    const float* __restrict__ fc1_w, const float* __restrict__ fc1_b,
    const float* __restrict__ fc2_w, const float* __restrict__ fc2_b,
    float* __restrict__ table)   // (16, 961)
{
  const int e  = blockIdx.x;          // 0..960
  const int di = e / 31 - 15;
  const int dj = e % 31 - 15;
  const float rx = (di > 0 ? 1.f : (di < 0 ? -1.f : 0.f)) * log1pf(fabsf((float)di));
  const float ry = (dj > 0 ? 1.f : (dj < 0 ? -1.f : 0.f)) * log1pf(fabsf((float)dj));
  const int lane = threadIdx.x;       // 0..63

  float acc[NH];
#pragma unroll
  for (int h = 0; h < NH; ++h) acc[h] = 0.f;

  for (int j = lane; j < 512; j += 64) {
    float hid = fmaf(fc1_w[2*j], rx, fmaf(fc1_w[2*j+1], ry, fc1_b[j]));
    hid = fmaxf(hid, 0.f);
#pragma unroll
    for (int h = 0; h < NH; ++h) acc[h] = fmaf(fc2_w[h*512 + j], hid, acc[h]);
  }
#pragma unroll
  for (int h = 0; h < NH; ++h) {
    float v = acc[h];
    for (int off = 32; off > 0; off >>= 1) v += __shfl_down(v, off);
    if (lane == 0) table[h*961 + e] = v + fc2_b[h];
  }
}

// ---------------------------------------------------------------------------
// Kernel 2/4: fp32 GEMM  C[m][n] = sum_k A[m][k]*W[n][k] + bias[n]
// (A: MxK row-major, W: NxK row-major — both contiguous along K)
// 256 threads, BM=BN=128, BK=16, 8x8 micro-tile, transposed LDS tiles
// so the inner loop uses ds_read_b128. blockIdx.x = n-tile (fast) so
// consecutive blocks share the same A panel in L2.
// ---------------------------------------------------------------------------
template<int BM, int BN, int BK>
__global__ __launch_bounds__(256) void gemm_nt_bias(
    const float* __restrict__ A, const float* __restrict__ W,
    const float* __restrict__ bias, float* __restrict__ Cmat,
    int M, int N, int K)
{
  constexpr int TM = 8, TN = 8;
  __shared__ __align__(16) float As[BK][BM + 4];
  __shared__ __align__(16) float Bs[BK][BN + 4];

  const int tid = threadIdx.x;
  const int tc  = tid & 15;          // n micro
  const int tr  = tid >> 4;          // m micro
  const size_t m0 = (size_t)blockIdx.y * BM;
  const size_t n0 = (size_t)blockIdx.x * BN;

  float acc[TM][TN];
#pragma unroll
  for (int i = 0; i < TM; ++i)
#pragma unroll
    for (int j = 0; j < TN; ++j) acc[i][j] = 0.f;

  const int lr = tid >> 2;           // 0..63
  const int lc = (tid & 3) * 4;      // 0,4,8,12   (BK = 16)

  for (int kt = 0; kt < K; kt += BK) {
    const float4 a0 = *(const float4*)&A[(m0 + lr)      * (size_t)K + kt + lc];
    const float4 a1 = *(const float4*)&A[(m0 + lr + 64) * (size_t)K + kt + lc];
    const float4 b0 = *(const float4*)&W[(n0 + lr)      * (size_t)K + kt + lc];
    const float4 b1 = *(const float4*)&W[(n0 + lr + 64) * (size_t)K + kt + lc];
    __syncthreads();   // previous iteration's readers done
    As[lc+0][lr]    = a0.x; As[lc+1][lr]    = a0.y; As[lc+2][lr]    = a0.z; As[lc+3][lr]    = a0.w;
    As[lc+0][lr+64] = a1.x; As[lc+1][lr+64] = a1.y; As[lc+2][lr+64] = a1.z; As[lc+3][lr+64] = a1.w;
    Bs[lc+0][lr]    = b0.x; Bs[lc+1][lr]    = b0.y; Bs[lc+2][lr]    = b0.z; Bs[lc+3][lr]    = b0.w;
    Bs[lc+0][lr+64] = b1.x; Bs[lc+1][lr+64] = b1.y; Bs[lc+2][lr+64] = b1.z; Bs[lc+3][lr+64] = b1.w;
    __syncthreads();
#pragma unroll
    for (int kk = 0; kk < BK; ++kk) {
      float av[TM], bv[TN];
      *(float4*)&av[0] = *(const float4*)&As[kk][tr*TM];
      *(float4*)&av[4] = *(const float4*)&As[kk][tr*TM + 4];
      *(float4*)&bv[0] = *(const float4*)&Bs[kk][tc*TN];
      *(float4*)&bv[4] = *(const float4*)&Bs[kk][tc*TN + 4];
#pragma unroll
      for (int i = 0; i < TM; ++i)
#pragma unroll
        for (int j = 0; j < TN; ++j)
          acc[i][j] = fmaf(av[i], bv[j], acc[i][j]);
    }
  }

#pragma unroll
  for (int i = 0; i < TM; ++i) {
    const size_t m = m0 + tr*TM + i;
#pragma unroll
    for (int j = 0; j < TN; j += 4) {
      const size_t n = n0 + tc*TN + j;
      float4 r;
      r.x = acc[i][j+0] + bias[n+0];
      r.y = acc[i][j+1] + bias[n+1];
      r.z = acc[i][j+2] + bias[n+2];
      r.w = acc[i][j+3] + bias[n+3];
      *(float4*)&Cmat[m * (size_t)N + n] = r;
    }
  }
}

// ---------------------------------------------------------------------------
// Kernel 3: cosine attention, one block per (window b_local, head h).
// Static LDS: normalized K (32KB) + V (32KB) = exactly 64KB.
// Bias slice read from global (H,961) table — 3.8KB/head, L1-resident.
// One query row per thread, online softmax with rescale-skip.
// ---------------------------------------------------------------------------
__global__ __launch_bounds__(256) void attn_kernel(
    const float* __restrict__ qkv,      // (CW*256, 1536): row = b_local*256+l, col = sel*512+h*32+d
    const float* __restrict__ table,    // (16, 961)
    const float* __restrict__ lscale,   // (16,)
    float* __restrict__ O)              // (CW*256, 512)
{
  __shared__ float kn[LTOK * DH];       // 32 KB
  __shared__ float vv[LTOK * DH];       // 32 KB  (total exactly 64 KB)

  const int b = blockIdx.x;             // local window index within chunk
  const int h = blockIdx.y;
  const int t = threadIdx.x;            // query row (also key row for staging)
  const float scale = __expf(fminf(lscale[h], LOG_MAX_F));
  const float* __restrict__ bt = table + h * 961;

  const size_t rowbase = ((size_t)(b*LTOK + t)) * (3*CCH) + h*DH;

  // --- stage K (L2-normalized) ---
  {
    float4 kr[8];
    float nk = 0.f;
#pragma unroll
    for (int c = 0; c < 8; ++c) {
      kr[c] = *(const float4*)&qkv[rowbase + CCH + c*4];
      nk += kr[c].x*kr[c].x + kr[c].y*kr[c].y + kr[c].z*kr[c].z + kr[c].w*kr[c].w;
    }
    const float ik = 1.f / fmaxf(sqrtf(nk), EPS_F);
#pragma unroll
    for (int c = 0; c < 8; ++c) {
      float4 w; w.x = kr[c].x*ik; w.y = kr[c].y*ik; w.z = kr[c].z*ik; w.w = kr[c].w*ik;
      *(float4*)&kn[t*DH + c*4] = w;
    }
  }
  // --- stage V ---
#pragma unroll
  for (int c = 0; c < 8; ++c)
    *(float4*)&vv[t*DH + c*4] = *(const float4*)&qkv[rowbase + 2*CCH + c*4];

  // --- load + L2-normalize q (logit scale folded in) ---
  float q[DH];
  {
    float4 qr[8];
    float nq = 0.f;
#pragma unroll
    for (int c = 0; c < 8; ++c) {
      qr[c] = *(const float4*)&qkv[rowbase + c*4];
      nq += qr[c].x*qr[c].x + qr[c].y*qr[c].y + qr[c].z*qr[c].z + qr[c].w*qr[c].w;
    }
    const float iq = scale / fmaxf(sqrtf(nq), EPS_F);
#pragma unroll
    for (int c = 0; c < 8; ++c) {
      q[4*c+0] = qr[c].x*iq; q[4*c+1] = qr[c].y*iq; q[4*c+2] = qr[c].z*iq; q[4*c+3] = qr[c].w*iq;
    }
  }
  __syncthreads();

  const int qi = t >> 4, qj = t & 15;
  float m = -INFINITY, l = 0.f;
  float o[DH];
#pragma unroll
  for (int dd = 0; dd < DH; ++dd) o[dd] = 0.f;

  for (int j = 0; j < LTOK; ++j) {
    const int ki = j >> 4, kj = j & 15;
    float s = bt[(qi - ki + 15) * 31 + (qj - kj + 15)];
    const float4* krow = (const float4*)&kn[j*DH];
#pragma unroll
    for (int c = 0; c < 8; ++c) {
      const float4 kk = krow[c];
      s = fmaf(q[4*c+0], kk.x, s);
      s = fmaf(q[4*c+1], kk.y, s);
      s = fmaf(q[4*c+2], kk.z, s);
      s = fmaf(q[4*c+3], kk.w, s);
    }
    float p;
    if (s > m) {                       // rescale only when the max grows
      const float corr = __expf(m - s);    // m=-inf on first iter -> 0
      l *= corr;
#pragma unroll
      for (int dd = 0; dd < DH; ++dd) o[dd] *= corr;
      m = s;
      p = 1.f;
    } else {
      p = __expf(s - m);
    }
    l += p;
    const float4* vrow = (const float4*)&vv[j*DH];
#pragma unroll
    for (int c = 0; c < 8; ++c) {
      const float4 vk = vrow[c];
      o[4*c+0] = fmaf(p, vk.x, o[4*c+0]);
      o[4*c+1] = fmaf(p, vk.y, o[4*c+1]);
      o[4*c+2] = fmaf(p, vk.z, o[4*c+2]);
      o[4*c+3] = fmaf(p, vk.w, o[4*c+3]);
    }
  }

  const float invl = 1.f / l;
  float* orow = &O[((size_t)(b*LTOK + t)) * CCH + h*DH];
#pragma unroll
  for (int c = 0; c < 8; ++c) {
    float4 r;
    r.x = o[4*c+0]*invl; r.y = o[4*c+1]*invl; r.z = o[4*c+2]*invl; r.w = o[4*c+3]*invl;
    *(float4*)&orow[c*4] = r;
  }
}

// ---------------------------------------------------------------------------
// Driver: adaptive chunking over windows so the scratch footprint fits ws_size.
// Per chunk of CW windows: qkv-GEMM -> attention -> proj-GEMM (rows of the
// proj are independent, so chunking is exact, not approximate).
// ---------------------------------------------------------------------------
extern "C" void kernel_launch(void* const* d_in, const int* in_sizes, int n_in,
                              void* d_out, int out_size, void* d_ws, size_t ws_size,
                              hipStream_t stream) {
  const float* x      = (const float*)d_in[0];
  const float* qkv_w  = (const float*)d_in[1];
  const float* qkv_b  = (const float*)d_in[2];
  const float* proj_w = (const float*)d_in[3];
  const float* proj_b = (const float*)d_in[4];
  const float* fc1_w  = (const float*)d_in[5];
  const float* fc1_b  = (const float*)d_in[6];
  const float* fc2_w  = (const float*)d_in[7];
  const float* fc2_b  = (const float*)d_in[8];
  const float* ls     = (const float*)d_in[9];
  float* out = (float*)d_out;

  // ws layout: table (16x961 fp32, 61504B) | qkv chunk | O chunk
  const size_t TBL_BYTES = (size_t)NH * 961 * 4;       // 61504, 16B-aligned
  const size_t PER_WIN   = (size_t)LTOK * (3*CCH + CCH) * 4;  // 2 MiB per window

  int CW = NBW;                                        // windows per chunk
  while (CW > 4 && TBL_BYTES + (size_t)CW * PER_WIN > ws_size) CW >>= 1;

  float* table  = (float*)d_ws;
  float* qkvbuf = table + NH * 961;
  float* Obuf   = qkvbuf + (size_t)CW * LTOK * (3*CCH);

  // 1) bias MLP table (961 unique rel coords x 16 heads), once
  bias_mlp_kernel<<<dim3(961), dim3(64), 0, stream>>>(fc1_w, fc1_b, fc2_w, fc2_b, table);

  const int Mc = CW * LTOK;                            // rows per chunk
  for (int c0 = 0; c0 < NBW; c0 += CW) {
    const float* xc  = x   + (size_t)c0 * LTOK * CCH;
    float*       oc  = out + (size_t)c0 * LTOK * CCH;

    // 2) QKV projection for chunk: (Mc,512) @ (512,1536)^T + bias
    gemm_nt_bias<128,128,16><<<dim3((3*CCH)/128, Mc/128), dim3(256), 0, stream>>>(
        xc, qkv_w, qkv_b, qkvbuf, Mc, 3*CCH, CCH);

    // 3) attention per (window-in-chunk, head)
    attn_kernel<<<dim3(CW, NH), dim3(256), 0, stream>>>(qkvbuf, table, ls, Obuf);

    // 4) output projection for chunk: (Mc,512) @ (512,512)^T + bias
    gemm_nt_bias<128,128,16><<<dim3(CCH/128, Mc/128), dim3(256), 0, stream>>>(
        Obuf, proj_w, proj_b, oc, Mc, CCH, CCH);
  }
}

// Round 5
// 2124.797 us; speedup vs baseline: 1.2574x; 1.2574x over previous
//
#include <hip/hip_runtime.h>
#include <hip/hip_bf16.h>
#include <math.h>

#define WINS 16
#define LTOK 256      // window length L = 16*16
#define CCH  512
#define NH   16
#define DH   32
#define NBW  256
#define LOG_MAX_F 4.605170185988092f
#define EPS_F 1e-12f

typedef __attribute__((ext_vector_type(8))) short bf16x8;   // MFMA A/B frag (4 VGPR)
typedef __attribute__((ext_vector_type(4))) float f32x4;    // MFMA C/D frag

// round-to-nearest-even fp32 -> bf16 (bits)
__device__ __forceinline__ unsigned short bf16rne(float f) {
  unsigned int u = __float_as_uint(f);
  u += 0x7fffu + ((u >> 16) & 1u);
  return (unsigned short)(u >> 16);
}

// ---------------------------------------------------------------------------
// Kernel 0: split fp32 (rows x 512) into bf16 [hi | lo] (rows x 1024).
// hi = top-16-bits truncation (residual exact in fp32), lo = RNE(a - hi).
// a ~= hi + lo with product error ~2^-17 -> fp32-faithful 3-product GEMM.
// ---------------------------------------------------------------------------
__global__ __launch_bounds__(256) void split_kernel(
    const float* __restrict__ in, unsigned short* __restrict__ out, long nElem)
{
  long total4 = nElem >> 2;
  for (long i4 = (long)blockIdx.x * 256 + threadIdx.x; i4 < total4;
       i4 += (long)gridDim.x * 256) {
    long row = i4 >> 7;              // / (512/4)
    int  kq  = ((int)i4 & 127) << 2;
    float4 a = *(const float4*)&in[(row << 9) + kq];
    unsigned int b0 = __float_as_uint(a.x), b1 = __float_as_uint(a.y);
    unsigned int b2 = __float_as_uint(a.z), b3 = __float_as_uint(a.w);
    ushort4 hi = make_ushort4((unsigned short)(b0 >> 16), (unsigned short)(b1 >> 16),
                              (unsigned short)(b2 >> 16), (unsigned short)(b3 >> 16));
    float l0 = a.x - __uint_as_float(b0 & 0xffff0000u);
    float l1 = a.y - __uint_as_float(b1 & 0xffff0000u);
    float l2 = a.z - __uint_as_float(b2 & 0xffff0000u);
    float l3 = a.w - __uint_as_float(b3 & 0xffff0000u);
    ushort4 lo = make_ushort4(bf16rne(l0), bf16rne(l1), bf16rne(l2), bf16rne(l3));
    *(ushort4*)&out[row * 1024 + kq]       = hi;
    *(ushort4*)&out[row * 1024 + 512 + kq] = lo;
  }
}

// ---------------------------------------------------------------------------
// Kernel 1: relative-position-bias MLP table, layout (H=16, 961).
// ---------------------------------------------------------------------------
__global__ __launch_bounds__(64) void bias_mlp_kernel(
    const float* __restrict__ fc1_w, const float* __restrict__ fc1_b,
    const float* __restrict__ fc2_w, const float* __restrict__ fc2_b,
    float* __restrict__ table)   // (16, 961)
{
  const int e  = blockIdx.x;          // 0..960
  const int di = e / 31 - 15;
  const int dj = e % 31 - 15;
  const float rx = (di > 0 ? 1.f : (di < 0 ? -1.f : 0.f)) * log1pf(fabsf((float)di));
  const float ry = (dj > 0 ? 1.f : (dj < 0 ? -1.f : 0.f)) * log1pf(fabsf((float)dj));
  const int lane = threadIdx.x;       // 0..63

  float acc[NH];
#pragma unroll
  for (int h = 0; h < NH; ++h) acc[h] = 0.f;

  for (int j = lane; j < 512; j += 64) {
    float hid = fmaf(fc1_w[2*j], rx, fmaf(fc1_w[2*j+1], ry, fc1_b[j]));
    hid = fmaxf(hid, 0.f);
#pragma unroll
    for (int h = 0; h < NH; ++h) acc[h] = fmaf(fc2_w[h*512 + j], hid, acc[h]);
  }
#pragma unroll
  for (int h = 0; h < NH; ++h) {
    float v = acc[h];
    for (int off = 32; off > 0; off >>= 1) v += __shfl_down(v, off);
    if (lane == 0) table[h*961 + e] = v + fc2_b[h];
  }
}

// ---------------------------------------------------------------------------
// Kernel 2/4: bf16-split MFMA GEMM.  C[m][n] = sum_k A32[m][k]*W32[n][k] + bias[n]
// A,B inputs are pre-split [hi|lo] bf16, row stride 2K (=1024).
// Three K-thirds implement the 3-product split: A:[hi,hi,lo] x B:[hi,lo,hi].
// m97 structure: 128x128 tile, 4 waves (2x2, 64x64/wave, 4x4 frags of 16x16),
// BK=32, global_load_lds 16B staging, 2-barrier K-loop, XCD-swizzled blockIdx.
// ---------------------------------------------------------------------------
__global__ __launch_bounds__(256) void gemm_mfma_split(
    const unsigned short* __restrict__ A,  // (M, 2K) bf16 [hi|lo]
    const unsigned short* __restrict__ B,  // (N, 2K) bf16 [hi|lo]
    const float* __restrict__ bias,        // (N,)
    float* __restrict__ C,                 // (M, N) fp32
    int M, int N, int K)                   // K = original K (512)
{
  __shared__ unsigned short As[128 * 32];  // [row][k] bf16, 8 KB
  __shared__ unsigned short Bs[128 * 32];

  // XCD-aware swizzle (gridDim.x % 8 == 0 by construction): each XCD gets a
  // contiguous id range; n fast within -> A-panel reuse + weights L2-resident.
  const int nwg  = gridDim.x;
  const int id   = (blockIdx.x & 7) * (nwg >> 3) + (blockIdx.x >> 3);
  const int ntls = N >> 7;
  const int mt = id / ntls, nt = id % ntls;

  const int tid  = threadIdx.x;
  const int wave = tid >> 6;          // 0..3
  const int lane = tid & 63;
  const int wr = wave >> 1, wc = wave & 1;
  const size_t m0 = (size_t)mt * 128, n0 = (size_t)nt * 128;
  const int K2 = 2 * K;

  f32x4 acc[4][4];
#pragma unroll
  for (int i = 0; i < 4; ++i)
#pragma unroll
    for (int j = 0; j < 4; ++j) acc[i][j] = 0.f;

  // staging geometry: per wave 2 loads of 16 rows each (A and B):
  // lane l -> row (l>>2), 16B k-chunk (l&3); LDS linear = base + l*16
  const int srow = (lane >> 2);
  const int sko  = (lane & 3) * 8;    // bf16 elements

  for (int t3 = 0; t3 < 3; ++t3) {
    const int kaB = (t3 < 2) ? 0 : K;     // A third: hi,hi,lo
    const int kbB = (t3 == 1) ? K : 0;    // B third: hi,lo,hi
    for (int kt = 0; kt < K; kt += 32) {
      const int ka = kaB + kt, kb = kbB + kt;
      __syncthreads();                    // prev tile's readers done
#pragma unroll
      for (int L = 0; L < 2; ++L) {
        const int r0 = wave * 32 + L * 16;
        __builtin_amdgcn_global_load_lds(
            (const __attribute__((address_space(1))) unsigned int*)
                &A[(m0 + r0 + srow) * (size_t)K2 + ka + sko],
            (__attribute__((address_space(3))) unsigned int*)&As[r0 * 32],
            16, 0, 0);
        __builtin_amdgcn_global_load_lds(
            (const __attribute__((address_space(1))) unsigned int*)
                &B[(n0 + r0 + srow) * (size_t)K2 + kb + sko],
            (__attribute__((address_space(3))) unsigned int*)&Bs[r0 * 32],
            16, 0, 0);
      }
      asm volatile("s_waitcnt vmcnt(0)" ::: "memory");
      __syncthreads();                    // all staging landed

      // fragment reads: lane holds row (lane&15), k = 8*(lane>>4) + [0..7]
      const int fr = lane & 15, fk = (lane >> 4) * 8;
      bf16x8 af[4], bfr[4];
#pragma unroll
      for (int i = 0; i < 4; ++i)
        af[i] = *(const bf16x8*)&As[(wr * 64 + i * 16 + fr) * 32 + fk];
#pragma unroll
      for (int j = 0; j < 4; ++j)
        bfr[j] = *(const bf16x8*)&Bs[(wc * 64 + j * 16 + fr) * 32 + fk];
#pragma unroll
      for (int i = 0; i < 4; ++i)
#pragma unroll
        for (int j = 0; j < 4; ++j)
          acc[i][j] = __builtin_amdgcn_mfma_f32_16x16x32_bf16(
              af[i], bfr[j], acc[i][j], 0, 0, 0);
    }
  }

  // epilogue: D mapping col = lane&15, row = 4*(lane>>4) + r  [m89 verified]
  const int cr = (lane >> 4) * 4, cc = lane & 15;
#pragma unroll
  for (int j = 0; j < 4; ++j) {
    const size_t col = n0 + wc * 64 + j * 16 + cc;
    const float bv = bias[col];
#pragma unroll
    for (int i = 0; i < 4; ++i) {
      const size_t rbase = m0 + wr * 64 + i * 16 + cr;
#pragma unroll
      for (int r = 0; r < 4; ++r)
        C[(rbase + r) * (size_t)N + col] = acc[i][j][r] + bv;
    }
  }
}

// ---------------------------------------------------------------------------
// Kernel 3: cosine attention, one block per (window b_local, head h).
// Static LDS: normalized K (32KB) + V (32KB). Bias from global (H,961) table.
// One query row per thread, online softmax with rescale-skip.
// Output written DIRECTLY in split [hi|lo] bf16 form for the proj GEMM.
// ---------------------------------------------------------------------------
__global__ __launch_bounds__(256) void attn_kernel(
    const float* __restrict__ qkv,      // (CW*256, 1536)
    const float* __restrict__ table,    // (16, 961)
    const float* __restrict__ lscale,   // (16,)
    unsigned short* __restrict__ Osp)   // (CW*256, 1024) bf16 [hi|lo]
{
  __shared__ float kn[LTOK * DH];       // 32 KB
  __shared__ float vv[LTOK * DH];       // 32 KB

  const int b = blockIdx.x;
  const int h = blockIdx.y;
  const int t = threadIdx.x;
  const float scale = __expf(fminf(lscale[h], LOG_MAX_F));
  const float* __restrict__ bt = table + h * 961;

  const size_t rowbase = ((size_t)(b*LTOK + t)) * (3*CCH) + h*DH;

  // --- stage K (L2-normalized) ---
  {
    float4 kr[8];
    float nk = 0.f;
#pragma unroll
    for (int c = 0; c < 8; ++c) {
      kr[c] = *(const float4*)&qkv[rowbase + CCH + c*4];
      nk += kr[c].x*kr[c].x + kr[c].y*kr[c].y + kr[c].z*kr[c].z + kr[c].w*kr[c].w;
    }
    const float ik = 1.f / fmaxf(sqrtf(nk), EPS_F);
#pragma unroll
    for (int c = 0; c < 8; ++c) {
      float4 w; w.x = kr[c].x*ik; w.y = kr[c].y*ik; w.z = kr[c].z*ik; w.w = kr[c].w*ik;
      *(float4*)&kn[t*DH + c*4] = w;
    }
  }
  // --- stage V ---
#pragma unroll
  for (int c = 0; c < 8; ++c)
    *(float4*)&vv[t*DH + c*4] = *(const float4*)&qkv[rowbase + 2*CCH + c*4];

  // --- load + L2-normalize q (logit scale folded in) ---
  float q[DH];
  {
    float4 qr[8];
    float nq = 0.f;
#pragma unroll
    for (int c = 0; c < 8; ++c) {
      qr[c] = *(const float4*)&qkv[rowbase + c*4];
      nq += qr[c].x*qr[c].x + qr[c].y*qr[c].y + qr[c].z*qr[c].z + qr[c].w*qr[c].w;
    }
    const float iq = scale / fmaxf(sqrtf(nq), EPS_F);
#pragma unroll
    for (int c = 0; c < 8; ++c) {
      q[4*c+0] = qr[c].x*iq; q[4*c+1] = qr[c].y*iq; q[4*c+2] = qr[c].z*iq; q[4*c+3] = qr[c].w*iq;
    }
  }
  __syncthreads();

  const int qi = t >> 4, qj = t & 15;
  float m = -INFINITY, l = 0.f;
  float o[DH];
#pragma unroll
  for (int dd = 0; dd < DH; ++dd) o[dd] = 0.f;

  for (int j = 0; j < LTOK; ++j) {
    const int ki = j >> 4, kj = j & 15;
    float s = bt[(qi - ki + 15) * 31 + (qj - kj + 15)];
    const float4* krow = (const float4*)&kn[j*DH];
#pragma unroll
    for (int c = 0; c < 8; ++c) {
      const float4 kk = krow[c];
      s = fmaf(q[4*c+0], kk.x, s);
      s = fmaf(q[4*c+1], kk.y, s);
      s = fmaf(q[4*c+2], kk.z, s);
      s = fmaf(q[4*c+3], kk.w, s);
    }
    float p;
    if (s > m) {
      const float corr = __expf(m - s);    // m=-inf first iter -> 0
      l *= corr;
#pragma unroll
      for (int dd = 0; dd < DH; ++dd) o[dd] *= corr;
      m = s;
      p = 1.f;
    } else {
      p = __expf(s - m);
    }
    l += p;
    const float4* vrow = (const float4*)&vv[j*DH];
#pragma unroll
    for (int c = 0; c < 8; ++c) {
      const float4 vk = vrow[c];
      o[4*c+0] = fmaf(p, vk.x, o[4*c+0]);
      o[4*c+1] = fmaf(p, vk.y, o[4*c+1]);
      o[4*c+2] = fmaf(p, vk.z, o[4*c+2]);
      o[4*c+3] = fmaf(p, vk.w, o[4*c+3]);
    }
  }

  const float invl = 1.f / l;
  unsigned short* obase = &Osp[((size_t)(b*LTOK + t)) * 1024 + h*DH];
#pragma unroll
  for (int c = 0; c < 8; ++c) {
    float v0 = o[4*c+0]*invl, v1 = o[4*c+1]*invl, v2 = o[4*c+2]*invl, v3 = o[4*c+3]*invl;
    unsigned int u0 = __float_as_uint(v0), u1 = __float_as_uint(v1);
    unsigned int u2 = __float_as_uint(v2), u3 = __float_as_uint(v3);
    ushort4 hi = make_ushort4((unsigned short)(u0 >> 16), (unsigned short)(u1 >> 16),
                              (unsigned short)(u2 >> 16), (unsigned short)(u3 >> 16));
    float l0 = v0 - __uint_as_float(u0 & 0xffff0000u);
    float l1 = v1 - __uint_as_float(u1 & 0xffff0000u);
    float l2 = v2 - __uint_as_float(u2 & 0xffff0000u);
    float l3 = v3 - __uint_as_float(u3 & 0xffff0000u);
    ushort4 lo = make_ushort4(bf16rne(l0), bf16rne(l1), bf16rne(l2), bf16rne(l3));
    *(ushort4*)&obase[c*4]       = hi;
    *(ushort4*)&obase[512 + c*4] = lo;
  }
}

// ---------------------------------------------------------------------------
// Driver. ws layout: table(64KB) | qkv_w split (3MB) | proj_w split (1MB) |
// per-chunk: qkv fp32 (Mc x 1536) | x split (Mc x 1024 bf16) | O split (same).
// Adaptive CW keeps the footprint within ws_size.
// ---------------------------------------------------------------------------
extern "C" void kernel_launch(void* const* d_in, const int* in_sizes, int n_in,
                              void* d_out, int out_size, void* d_ws, size_t ws_size,
                              hipStream_t stream) {
  const float* x      = (const float*)d_in[0];
  const float* qkv_w  = (const float*)d_in[1];
  const float* qkv_b  = (const float*)d_in[2];
  const float* proj_w = (const float*)d_in[3];
  const float* proj_b = (const float*)d_in[4];
  const float* fc1_w  = (const float*)d_in[5];
  const float* fc1_b  = (const float*)d_in[6];
  const float* fc2_w  = (const float*)d_in[7];
  const float* fc2_b  = (const float*)d_in[8];
  const float* ls     = (const float*)d_in[9];
  float* out = (float*)d_out;

  const size_t FIXED   = 65536 + (size_t)1536*1024*2 + (size_t)512*1024*2;
  const size_t PER_WIN = (size_t)LTOK*(3*CCH)*4 + 2*(size_t)LTOK*1024*2; // 2.5 MiB

  int CW = NBW;
  while (CW > 4 && FIXED + (size_t)CW * PER_WIN > ws_size) CW >>= 1;

  char* p = (char*)d_ws;
  float*          table   = (float*)p;          p += 65536;
  unsigned short* qkvw_s  = (unsigned short*)p; p += (size_t)1536*1024*2;
  unsigned short* projw_s = (unsigned short*)p; p += (size_t)512*1024*2;
  float*          qkvbuf  = (float*)p;          p += (size_t)CW*LTOK*(3*CCH)*4;
  unsigned short* xsplit  = (unsigned short*)p; p += (size_t)CW*LTOK*1024*2;
  unsigned short* osplit  = (unsigned short*)p;

  // bias table + weight splits (once per call)
  bias_mlp_kernel<<<dim3(961), dim3(64), 0, stream>>>(fc1_w, fc1_b, fc2_w, fc2_b, table);
  split_kernel<<<dim3(768), dim3(256), 0, stream>>>(qkv_w, qkvw_s, (long)1536*512);
  split_kernel<<<dim3(256), dim3(256), 0, stream>>>(proj_w, projw_s, (long)512*512);

  const int Mc = CW * LTOK;
  const long xElems = (long)Mc * CCH;
  const int splitGrid = (int)((xElems/4 + 255) / 256) > 2048 ? 2048
                        : (int)((xElems/4 + 255) / 256);

  for (int c0 = 0; c0 < NBW; c0 += CW) {
    const float* xc = x   + (size_t)c0 * LTOK * CCH;
    float*       oc = out + (size_t)c0 * LTOK * CCH;

    // split x chunk -> [hi|lo] bf16
    split_kernel<<<dim3(splitGrid), dim3(256), 0, stream>>>(xc, xsplit, xElems);

    // QKV projection: (Mc,512) @ (1536,512)^T + bias, via split-bf16 MFMA
    gemm_mfma_split<<<dim3((Mc/128) * (1536/128)), dim3(256), 0, stream>>>(
        xsplit, qkvw_s, qkv_b, qkvbuf, Mc, 1536, CCH);

    // attention per (window-in-chunk, head); writes O in split form
    attn_kernel<<<dim3(CW, NH), dim3(256), 0, stream>>>(qkvbuf, table, ls, osplit);

    // output projection: (Mc,512) @ (512,512)^T + bias
    gemm_mfma_split<<<dim3((Mc/128) * (512/128)), dim3(256), 0, stream>>>(
        osplit, projw_s, proj_b, oc, Mc, 512, CCH);
  }
}

// Round 6
// 1161.824 us; speedup vs baseline: 2.2996x; 1.8288x over previous
//
#include <hip/hip_runtime.h>
#include <hip/hip_bf16.h>
#include <math.h>

#define WINS 16
#define LTOK 256      // window length L = 16*16
#define CCH  512
#define NH   16
#define DH   32
#define NBW  256
#define LOG_MAX_F 4.605170185988092f
#define EPS_F 1e-12f

typedef __attribute__((ext_vector_type(8))) short bf16x8;   // MFMA A/B frag (4 VGPR)
typedef __attribute__((ext_vector_type(4))) float f32x4;    // MFMA C/D frag

// round-to-nearest-even fp32 -> bf16 (bits)
__device__ __forceinline__ unsigned short bf16rne(float f) {
  unsigned int u = __float_as_uint(f);
  u += 0x7fffu + ((u >> 16) & 1u);
  return (unsigned short)(u >> 16);
}
__device__ __forceinline__ float bf2f(unsigned short s) {
  return __uint_as_float(((unsigned int)s) << 16);
}

// lgkmcnt(0) + scheduler fence (rule #18: asm waitcnt needs sched_barrier)
#define LGKM0 do { asm volatile("s_waitcnt lgkmcnt(0)" ::: "memory"); \
                   __builtin_amdgcn_sched_barrier(0); } while (0)

// ---------------------------------------------------------------------------
// Kernel 0: split fp32 (rows x 512) into bf16 [hi | lo] (rows x 1024).
// ---------------------------------------------------------------------------
__global__ __launch_bounds__(256) void split_kernel(
    const float* __restrict__ in, unsigned short* __restrict__ out, long nElem)
{
  long total4 = nElem >> 2;
  for (long i4 = (long)blockIdx.x * 256 + threadIdx.x; i4 < total4;
       i4 += (long)gridDim.x * 256) {
    long row = i4 >> 7;              // / (512/4)
    int  kq  = ((int)i4 & 127) << 2;
    float4 a = *(const float4*)&in[(row << 9) + kq];
    unsigned int b0 = __float_as_uint(a.x), b1 = __float_as_uint(a.y);
    unsigned int b2 = __float_as_uint(a.z), b3 = __float_as_uint(a.w);
    ushort4 hi = make_ushort4((unsigned short)(b0 >> 16), (unsigned short)(b1 >> 16),
                              (unsigned short)(b2 >> 16), (unsigned short)(b3 >> 16));
    float l0 = a.x - __uint_as_float(b0 & 0xffff0000u);
    float l1 = a.y - __uint_as_float(b1 & 0xffff0000u);
    float l2 = a.z - __uint_as_float(b2 & 0xffff0000u);
    float l3 = a.w - __uint_as_float(b3 & 0xffff0000u);
    ushort4 lo = make_ushort4(bf16rne(l0), bf16rne(l1), bf16rne(l2), bf16rne(l3));
    *(ushort4*)&out[row * 1024 + kq]       = hi;
    *(ushort4*)&out[row * 1024 + 512 + kq] = lo;
  }
}

// ---------------------------------------------------------------------------
// Kernel 1: relative-position-bias MLP table, layout (H=16, 961).
// ---------------------------------------------------------------------------
__global__ __launch_bounds__(64) void bias_mlp_kernel(
    const float* __restrict__ fc1_w, const float* __restrict__ fc1_b,
    const float* __restrict__ fc2_w, const float* __restrict__ fc2_b,
    float* __restrict__ table)   // (16, 961)
{
  const int e  = blockIdx.x;          // 0..960
  const int di = e / 31 - 15;
  const int dj = e % 31 - 15;
  const float rx = (di > 0 ? 1.f : (di < 0 ? -1.f : 0.f)) * log1pf(fabsf((float)di));
  const float ry = (dj > 0 ? 1.f : (dj < 0 ? -1.f : 0.f)) * log1pf(fabsf((float)dj));
  const int lane = threadIdx.x;       // 0..63

  float acc[NH];
#pragma unroll
  for (int h = 0; h < NH; ++h) acc[h] = 0.f;

  for (int j = lane; j < 512; j += 64) {
    float hid = fmaf(fc1_w[2*j], rx, fmaf(fc1_w[2*j+1], ry, fc1_b[j]));
    hid = fmaxf(hid, 0.f);
#pragma unroll
    for (int h = 0; h < NH; ++h) acc[h] = fmaf(fc2_w[h*512 + j], hid, acc[h]);
  }
#pragma unroll
  for (int h = 0; h < NH; ++h) {
    float v = acc[h];
    for (int off = 32; off > 0; off >>= 1) v += __shfl_down(v, off);
    if (lane == 0) table[h*961 + e] = v + fc2_b[h];
  }
}

// ---------------------------------------------------------------------------
// Kernel 1b: per-head softmax upper bound M_h = scale_h + max_e bias_h[e] + eps.
// Since q,k are L2-normalized, s = scale*cos + bias <= M_h always -> single-pass
// softmax exp(s - M_h), no online max, no divergence.
// ---------------------------------------------------------------------------
__global__ __launch_bounds__(256) void mh_kernel(
    const float* __restrict__ table, const float* __restrict__ lscale,
    float* __restrict__ Mh)
{
  const int t = threadIdx.x, h = t >> 4, l16 = t & 15;
  float bm = -1e30f;
  for (int e = l16; e < 961; e += 16) bm = fmaxf(bm, table[h*961 + e]);
#pragma unroll
  for (int off = 1; off < 16; off <<= 1) bm = fmaxf(bm, __shfl_xor(bm, off));
  if (l16 == 0)
    Mh[h] = __expf(fminf(lscale[h], LOG_MAX_F)) + bm + 1e-3f;
}

// ---------------------------------------------------------------------------
// Kernel 2/4: bf16-split MFMA GEMM (verified round 5, unchanged).
// ---------------------------------------------------------------------------
__global__ __launch_bounds__(256) void gemm_mfma_split(
    const unsigned short* __restrict__ A,  // (M, 2K) bf16 [hi|lo]
    const unsigned short* __restrict__ B,  // (N, 2K) bf16 [hi|lo]
    const float* __restrict__ bias,        // (N,)
    float* __restrict__ C,                 // (M, N) fp32
    int M, int N, int K)                   // K = original K (512)
{
  __shared__ unsigned short As[128 * 32];
  __shared__ unsigned short Bs[128 * 32];

  const int nwg  = gridDim.x;
  const int id   = (blockIdx.x & 7) * (nwg >> 3) + (blockIdx.x >> 3);
  const int ntls = N >> 7;
  const int mt = id / ntls, nt = id % ntls;

  const int tid  = threadIdx.x;
  const int wave = tid >> 6;
  const int lane = tid & 63;
  const int wr = wave >> 1, wc = wave & 1;
  const size_t m0 = (size_t)mt * 128, n0 = (size_t)nt * 128;
  const int K2 = 2 * K;

  f32x4 acc[4][4];
#pragma unroll
  for (int i = 0; i < 4; ++i)
#pragma unroll
    for (int j = 0; j < 4; ++j) acc[i][j] = 0.f;

  const int srow = (lane >> 2);
  const int sko  = (lane & 3) * 8;

  for (int t3 = 0; t3 < 3; ++t3) {
    const int kaB = (t3 < 2) ? 0 : K;     // A third: hi,hi,lo
    const int kbB = (t3 == 1) ? K : 0;    // B third: hi,lo,hi
    for (int kt = 0; kt < K; kt += 32) {
      const int ka = kaB + kt, kb = kbB + kt;
      __syncthreads();
#pragma unroll
      for (int L = 0; L < 2; ++L) {
        const int r0 = wave * 32 + L * 16;
        __builtin_amdgcn_global_load_lds(
            (const __attribute__((address_space(1))) unsigned int*)
                &A[(m0 + r0 + srow) * (size_t)K2 + ka + sko],
            (__attribute__((address_space(3))) unsigned int*)&As[r0 * 32],
            16, 0, 0);
        __builtin_amdgcn_global_load_lds(
            (const __attribute__((address_space(1))) unsigned int*)
                &B[(n0 + r0 + srow) * (size_t)K2 + kb + sko],
            (__attribute__((address_space(3))) unsigned int*)&Bs[r0 * 32],
            16, 0, 0);
      }
      asm volatile("s_waitcnt vmcnt(0)" ::: "memory");
      __syncthreads();

      const int fr = lane & 15, fk = (lane >> 4) * 8;
      bf16x8 af[4], bfr[4];
#pragma unroll
      for (int i = 0; i < 4; ++i)
        af[i] = *(const bf16x8*)&As[(wr * 64 + i * 16 + fr) * 32 + fk];
#pragma unroll
      for (int j = 0; j < 4; ++j)
        bfr[j] = *(const bf16x8*)&Bs[(wc * 64 + j * 16 + fr) * 32 + fk];
#pragma unroll
      for (int i = 0; i < 4; ++i)
#pragma unroll
        for (int j = 0; j < 4; ++j)
          acc[i][j] = __builtin_amdgcn_mfma_f32_16x16x32_bf16(
              af[i], bfr[j], acc[i][j], 0, 0, 0);
    }
  }

  const int cr = (lane >> 4) * 4, cc = lane & 15;
#pragma unroll
  for (int j = 0; j < 4; ++j) {
    const size_t col = n0 + wc * 64 + j * 16 + cc;
    const float bv = bias[col];
#pragma unroll
    for (int i = 0; i < 4; ++i) {
      const size_t rbase = m0 + wr * 64 + i * 16 + cr;
#pragma unroll
      for (int r = 0; r < 4; ++r)
        C[(rbase + r) * (size_t)N + col] = acc[i][j][r] + bv;
    }
  }
}

// ---------------------------------------------------------------------------
// Kernel 3: MFMA cosine attention. One block = (window b, head h), 4 waves,
// 64 queries/wave. Swapped QK^T (A=K, B=Q) with hi/lo 3-product split;
// bound-based single-pass softmax (M_h); PV via MFMA with P bf16-RNE bounced
// through wave-private LDS and V^T bf16-RNE in LDS.
//   Khi/Klo: [key][d] padded 80B rows (2-way = free).
//   Vth:     [d][key] padded 528B rows (2-way = free).
//   Pql:     per-wave 16q x 32keys, 64B rows, chunk-XOR swizzle.
// Output written in split [hi|lo] bf16 form for the proj GEMM.
// ---------------------------------------------------------------------------
__global__ __launch_bounds__(256) void attn_kernel(
    const float* __restrict__ qkv,      // (CW*256, 1536)
    const float* __restrict__ table,    // (16, 961) fp32
    const float* __restrict__ lscale,   // (16,)
    const float* __restrict__ Mh,       // (16,)
    unsigned short* __restrict__ Osp)   // (CW*256, 1024) bf16 [hi|lo]
{
  __shared__ unsigned short Khi[256 * 40];   // 20 KB
  __shared__ unsigned short Klo[256 * 40];   // 20 KB
  __shared__ unsigned short Vth[32 * 264];   // 16.5 KB
  __shared__ unsigned short Pql[4 * 512];    // 4 KB (1 KB per wave)
  __shared__ unsigned short btb[962];        // 1.9 KB bias (bf16)

  const int b = blockIdx.x, h = blockIdx.y, t = threadIdx.x;
  const int lane = t & 63, w = t >> 6;
  const int G = lane >> 4, ql = lane & 15;
  const float scale = __expf(fminf(lscale[h], LOG_MAX_F));
  const float Mhv = Mh[h];

  // ---- stage K row t: L2-normalize, hi/lo split ----
  {
    const size_t rb = ((size_t)(b*LTOK + t)) * (3*CCH) + CCH + h*DH;
    float4 kr[8]; float nk = 0.f;
#pragma unroll
    for (int c = 0; c < 8; ++c) {
      kr[c] = *(const float4*)&qkv[rb + c*4];
      nk += kr[c].x*kr[c].x + kr[c].y*kr[c].y + kr[c].z*kr[c].z + kr[c].w*kr[c].w;
    }
    const float ik = 1.f / fmaxf(sqrtf(nk), EPS_F);
#pragma unroll
    for (int c = 0; c < 4; ++c) {
      float f[8] = {kr[2*c].x*ik, kr[2*c].y*ik, kr[2*c].z*ik, kr[2*c].w*ik,
                    kr[2*c+1].x*ik, kr[2*c+1].y*ik, kr[2*c+1].z*ik, kr[2*c+1].w*ik};
      bf16x8 hi, lo;
#pragma unroll
      for (int j = 0; j < 8; ++j) {
        unsigned int u = __float_as_uint(f[j]);
        hi[j] = (short)(u >> 16);
        lo[j] = (short)bf16rne(f[j] - __uint_as_float(u & 0xffff0000u));
      }
      *(bf16x8*)&Khi[t*40 + c*8] = hi;
      *(bf16x8*)&Klo[t*40 + c*8] = lo;
    }
  }
  // ---- stage V row t: bf16-RNE, transposed [d][key] ----
  {
    const size_t rb = ((size_t)(b*LTOK + t)) * (3*CCH) + 2*CCH + h*DH;
#pragma unroll
    for (int c = 0; c < 8; ++c) {
      float4 v = *(const float4*)&qkv[rb + c*4];
      Vth[(4*c+0)*264 + t] = bf16rne(v.x);
      Vth[(4*c+1)*264 + t] = bf16rne(v.y);
      Vth[(4*c+2)*264 + t] = bf16rne(v.z);
      Vth[(4*c+3)*264 + t] = bf16rne(v.w);
    }
  }
  // ---- stage bias (bf16) ----
  for (int e = t; e < 961; e += 256) btb[e] = bf16rne(table[h*961 + e]);

  // ---- Q fragments in registers: [qt] hi/lo, scale & 1/norm folded ----
  bf16x8 Qh[4], Qlr[4];
#pragma unroll
  for (int qt = 0; qt < 4; ++qt) {
    const int qrow = b*LTOK + w*64 + qt*16 + ql;
    const float* qp = &qkv[(size_t)qrow * (3*CCH) + h*DH + G*8];
    float4 a = *(const float4*)qp;
    float4 b4 = *(const float4*)(qp + 4);
    float ss = a.x*a.x + a.y*a.y + a.z*a.z + a.w*a.w
             + b4.x*b4.x + b4.y*b4.y + b4.z*b4.z + b4.w*b4.w;
    ss += __shfl_xor(ss, 16);
    ss += __shfl_xor(ss, 32);
    const float iq = scale / fmaxf(sqrtf(ss), EPS_F);
    float f[8] = {a.x*iq, a.y*iq, a.z*iq, a.w*iq, b4.x*iq, b4.y*iq, b4.z*iq, b4.w*iq};
#pragma unroll
    for (int j = 0; j < 8; ++j) {
      unsigned int u = __float_as_uint(f[j]);
      Qh[qt][j]  = (short)(u >> 16);
      Qlr[qt][j] = (short)bf16rne(f[j] - __uint_as_float(u & 0xffff0000u));
    }
  }
  __syncthreads();

  f32x4 accO[2][4];
#pragma unroll
  for (int i = 0; i < 2; ++i)
#pragma unroll
    for (int j = 0; j < 4; ++j) accO[i][j] = 0.f;
  float lsum[4] = {0.f, 0.f, 0.f, 0.f};

  const int pbase = w * 512;   // wave-private P region (ushort units)

  for (int kp = 0; kp < 8; ++kp) {
    // K A-frags (2 key-tiles) and V^T A-frags (2 d-tiles), reused across qt
    bf16x8 kh[2], kl[2], vf[2];
#pragma unroll
    for (int tt = 0; tt < 2; ++tt) {
      const int krow = kp*32 + tt*16 + ql;
      kh[tt] = *(const bf16x8*)&Khi[krow*40 + G*8];
      kl[tt] = *(const bf16x8*)&Klo[krow*40 + G*8];
    }
#pragma unroll
    for (int dt = 0; dt < 2; ++dt)
      vf[dt] = *(const bf16x8*)&Vth[(dt*16 + ql)*264 + kp*32 + G*8];

#pragma unroll
    for (int qt = 0; qt < 4; ++qt) {
      // --- S^T tiles: 3-product split, D[key_in_tile, q] ---
      f32x4 st0, st1; st0 = 0.f; st1 = 0.f;
      st0 = __builtin_amdgcn_mfma_f32_16x16x32_bf16(kl[0], Qh[qt],  st0, 0,0,0);
      st0 = __builtin_amdgcn_mfma_f32_16x16x32_bf16(kh[0], Qlr[qt], st0, 0,0,0);
      st0 = __builtin_amdgcn_mfma_f32_16x16x32_bf16(kh[0], Qh[qt],  st0, 0,0,0);
      st1 = __builtin_amdgcn_mfma_f32_16x16x32_bf16(kl[1], Qh[qt],  st1, 0,0,0);
      st1 = __builtin_amdgcn_mfma_f32_16x16x32_bf16(kh[1], Qlr[qt], st1, 0,0,0);
      st1 = __builtin_amdgcn_mfma_f32_16x16x32_bf16(kh[1], Qh[qt],  st1, 0,0,0);

      // --- bias + bound-softmax + bf16 pack ---
      const int qg = w*64 + qt*16 + ql;
      const int qi = qg >> 4, qj = qg & 15;
      unsigned short ph[2][4];
#pragma unroll
      for (int tt = 0; tt < 2; ++tt) {
        const int ki = kp*2 + tt;
#pragma unroll
        for (int r = 0; r < 4; ++r) {
          const int kj = 4*G + r;
          const float bv = bf2f(btb[(qi - ki + 15)*31 + (qj - kj + 15)]);
          const float sv = (tt == 0) ? st0[r] : st1[r];
          const float p = __expf(sv + bv - Mhv);
          const unsigned short us = bf16rne(p);
          ph[tt][r] = us;
          lsum[qt] += bf2f(us);          // sum the SAME rounded p used in PV
        }
      }

      LGKM0;   // prior P-frag reads (previous qt) retired before overwrite
#pragma unroll
      for (int tt = 0; tt < 2; ++tt) {
        const int chunkw = 2*tt + (G >> 1);
        const int widx = pbase + ql*32 + ((chunkw ^ (ql & 3)) * 8) + (G & 1)*4;
        *(ushort4*)&Pql[widx] = make_ushort4(ph[tt][0], ph[tt][1], ph[tt][2], ph[tt][3]);
      }
      LGKM0;   // P writes visible before B-frag read

      const bf16x8 pb = *(const bf16x8*)&Pql[pbase + ql*32 + ((G ^ (ql & 3)) * 8)];
      accO[0][qt] = __builtin_amdgcn_mfma_f32_16x16x32_bf16(vf[0], pb, accO[0][qt], 0,0,0);
      accO[1][qt] = __builtin_amdgcn_mfma_f32_16x16x32_bf16(vf[1], pb, accO[1][qt], 0,0,0);
    }
  }

  // ---- epilogue: 1/l, split-write O ----
#pragma unroll
  for (int qt = 0; qt < 4; ++qt) {
    float lq = lsum[qt];
    lq += __shfl_xor(lq, 16);
    lq += __shfl_xor(lq, 32);
    const float inv = 1.f / fmaxf(lq, 1e-37f);
    const int qrow = b*LTOK + w*64 + qt*16 + ql;
#pragma unroll
    for (int dt = 0; dt < 2; ++dt) {
      unsigned short hv[4], lv[4];
#pragma unroll
      for (int r = 0; r < 4; ++r) {
        const float v = accO[dt][qt][r] * inv;
        const unsigned int u = __float_as_uint(v);
        hv[r] = (unsigned short)(u >> 16);
        lv[r] = bf16rne(v - __uint_as_float(u & 0xffff0000u));
      }
      unsigned short* ob = &Osp[(size_t)qrow * 1024 + h*DH + dt*16 + G*4];
      *(ushort4*)ob         = make_ushort4(hv[0], hv[1], hv[2], hv[3]);
      *(ushort4*)(ob + 512) = make_ushort4(lv[0], lv[1], lv[2], lv[3]);
    }
  }
}

// ---------------------------------------------------------------------------
// Driver. ws: table(61504B)+Mh(64B) in 64KB | qkv_w split | proj_w split |
// per-chunk: qkv fp32 | O split. Adaptive CW fits ws_size.
// ---------------------------------------------------------------------------
extern "C" void kernel_launch(void* const* d_in, const int* in_sizes, int n_in,
                              void* d_out, int out_size, void* d_ws, size_t ws_size,
                              hipStream_t stream) {
  const float* x      = (const float*)d_in[0];
  const float* qkv_w  = (const float*)d_in[1];
  const float* qkv_b  = (const float*)d_in[2];
  const float* proj_w = (const float*)d_in[3];
  const float* proj_b = (const float*)d_in[4];
  const float* fc1_w  = (const float*)d_in[5];
  const float* fc1_b  = (const float*)d_in[6];
  const float* fc2_w  = (const float*)d_in[7];
  const float* fc2_b  = (const float*)d_in[8];
  const float* ls     = (const float*)d_in[9];
  float* out = (float*)d_out;

  const size_t FIXED   = 65536 + (size_t)1536*1024*2 + (size_t)512*1024*2;
  const size_t PER_WIN = (size_t)LTOK*(3*CCH)*4 + 2*(size_t)LTOK*1024*2; // 2.5 MiB

  int CW = NBW;
  while (CW > 4 && FIXED + (size_t)CW * PER_WIN > ws_size) CW >>= 1;

  char* p = (char*)d_ws;
  float*          table   = (float*)p;          p += 65536;
  unsigned short* qkvw_s  = (unsigned short*)p; p += (size_t)1536*1024*2;
  unsigned short* projw_s = (unsigned short*)p; p += (size_t)512*1024*2;
  float*          qkvbuf  = (float*)p;          p += (size_t)CW*LTOK*(3*CCH)*4;
  unsigned short* xsplit  = (unsigned short*)p; p += (size_t)CW*LTOK*1024*2;
  unsigned short* osplit  = (unsigned short*)p;
  float*          MhPtr   = table + NH*961;     // inside the 64KB table region

  // bias table + M_h + weight splits (once per call)
  bias_mlp_kernel<<<dim3(961), dim3(64), 0, stream>>>(fc1_w, fc1_b, fc2_w, fc2_b, table);
  mh_kernel<<<dim3(1), dim3(256), 0, stream>>>(table, ls, MhPtr);
  split_kernel<<<dim3(768), dim3(256), 0, stream>>>(qkv_w, qkvw_s, (long)1536*512);
  split_kernel<<<dim3(256), dim3(256), 0, stream>>>(proj_w, projw_s, (long)512*512);

  const int Mc = CW * LTOK;
  const long xElems = (long)Mc * CCH;
  const int splitGrid = (int)((xElems/4 + 255) / 256) > 2048 ? 2048
                        : (int)((xElems/4 + 255) / 256);

  for (int c0 = 0; c0 < NBW; c0 += CW) {
    const float* xc = x   + (size_t)c0 * LTOK * CCH;
    float*       oc = out + (size_t)c0 * LTOK * CCH;

    // split x chunk -> [hi|lo] bf16
    split_kernel<<<dim3(splitGrid), dim3(256), 0, stream>>>(xc, xsplit, xElems);

    // QKV projection: (Mc,512) @ (1536,512)^T + bias, split-bf16 MFMA
    gemm_mfma_split<<<dim3((Mc/128) * (1536/128)), dim3(256), 0, stream>>>(
        xsplit, qkvw_s, qkv_b, qkvbuf, Mc, 1536, CCH);

    // MFMA attention per (window-in-chunk, head); writes O in split form
    attn_kernel<<<dim3(CW, NH), dim3(256), 0, stream>>>(
        qkvbuf, table, ls, MhPtr, osplit);

    // output projection: (Mc,512) @ (512,512)^T + bias
    gemm_mfma_split<<<dim3((Mc/128) * (512/128)), dim3(256), 0, stream>>>(
        osplit, projw_s, proj_b, oc, Mc, 512, CCH);
  }
}

// Round 7
// 956.419 us; speedup vs baseline: 2.7935x; 1.2148x over previous
//
#include <hip/hip_runtime.h>
#include <hip/hip_bf16.h>
#include <math.h>

#define WINS 16
#define LTOK 256      // window length L = 16*16
#define CCH  512
#define NH   16
#define DH   32
#define NBW  256
#define LOG_MAX_F 4.605170185988092f
#define EPS_F 1e-12f

typedef __attribute__((ext_vector_type(8))) short bf16x8;   // MFMA A/B frag (4 VGPR)
typedef __attribute__((ext_vector_type(4))) float f32x4;    // MFMA C/D frag

// round-to-nearest-even fp32 -> bf16 (bits)
__device__ __forceinline__ unsigned short bf16rne(float f) {
  unsigned int u = __float_as_uint(f);
  u += 0x7fffu + ((u >> 16) & 1u);
  return (unsigned short)(u >> 16);
}
__device__ __forceinline__ float bf2f(unsigned short s) {
  return __uint_as_float(((unsigned int)s) << 16);
}

// ---------------------------------------------------------------------------
// Kernel 0: split fp32 (rows x 512) into bf16 [hi | lo] (rows x 1024).
// ---------------------------------------------------------------------------
__global__ __launch_bounds__(256) void split_kernel(
    const float* __restrict__ in, unsigned short* __restrict__ out, long nElem)
{
  long total4 = nElem >> 2;
  for (long i4 = (long)blockIdx.x * 256 + threadIdx.x; i4 < total4;
       i4 += (long)gridDim.x * 256) {
    long row = i4 >> 7;              // / (512/4)
    int  kq  = ((int)i4 & 127) << 2;
    float4 a = *(const float4*)&in[(row << 9) + kq];
    unsigned int b0 = __float_as_uint(a.x), b1 = __float_as_uint(a.y);
    unsigned int b2 = __float_as_uint(a.z), b3 = __float_as_uint(a.w);
    ushort4 hi = make_ushort4((unsigned short)(b0 >> 16), (unsigned short)(b1 >> 16),
                              (unsigned short)(b2 >> 16), (unsigned short)(b3 >> 16));
    float l0 = a.x - __uint_as_float(b0 & 0xffff0000u);
    float l1 = a.y - __uint_as_float(b1 & 0xffff0000u);
    float l2 = a.z - __uint_as_float(b2 & 0xffff0000u);
    float l3 = a.w - __uint_as_float(b3 & 0xffff0000u);
    ushort4 lo = make_ushort4(bf16rne(l0), bf16rne(l1), bf16rne(l2), bf16rne(l3));
    *(ushort4*)&out[row * 1024 + kq]       = hi;
    *(ushort4*)&out[row * 1024 + 512 + kq] = lo;
  }
}

// ---------------------------------------------------------------------------
// Kernel 1: relative-position-bias MLP table, layout (H=16, 961).
// ---------------------------------------------------------------------------
__global__ __launch_bounds__(64) void bias_mlp_kernel(
    const float* __restrict__ fc1_w, const float* __restrict__ fc1_b,
    const float* __restrict__ fc2_w, const float* __restrict__ fc2_b,
    float* __restrict__ table)   // (16, 961)
{
  const int e  = blockIdx.x;          // 0..960
  const int di = e / 31 - 15;
  const int dj = e % 31 - 15;
  const float rx = (di > 0 ? 1.f : (di < 0 ? -1.f : 0.f)) * log1pf(fabsf((float)di));
  const float ry = (dj > 0 ? 1.f : (dj < 0 ? -1.f : 0.f)) * log1pf(fabsf((float)dj));
  const int lane = threadIdx.x;       // 0..63

  float acc[NH];
#pragma unroll
  for (int h = 0; h < NH; ++h) acc[h] = 0.f;

  for (int j = lane; j < 512; j += 64) {
    float hid = fmaf(fc1_w[2*j], rx, fmaf(fc1_w[2*j+1], ry, fc1_b[j]));
    hid = fmaxf(hid, 0.f);
#pragma unroll
    for (int h = 0; h < NH; ++h) acc[h] = fmaf(fc2_w[h*512 + j], hid, acc[h]);
  }
#pragma unroll
  for (int h = 0; h < NH; ++h) {
    float v = acc[h];
    for (int off = 32; off > 0; off >>= 1) v += __shfl_down(v, off);
    if (lane == 0) table[h*961 + e] = v + fc2_b[h];
  }
}

// ---------------------------------------------------------------------------
// Kernel 1b: per-head softmax upper bound M_h = scale_h + max_e bias_h[e] + eps.
// ---------------------------------------------------------------------------
__global__ __launch_bounds__(256) void mh_kernel(
    const float* __restrict__ table, const float* __restrict__ lscale,
    float* __restrict__ Mh)
{
  const int t = threadIdx.x, h = t >> 4, l16 = t & 15;
  float bm = -1e30f;
  for (int e = l16; e < 961; e += 16) bm = fmaxf(bm, table[h*961 + e]);
#pragma unroll
  for (int off = 1; off < 16; off <<= 1) bm = fmaxf(bm, __shfl_xor(bm, off));
  if (l16 == 0)
    Mh[h] = __expf(fminf(lscale[h], LOG_MAX_F)) + bm + 1e-3f;
}

// ---------------------------------------------------------------------------
// Kernel 2/4: bf16-split MFMA GEMM, single K-sweep.
// Per 32-K step: stage Ahi/Alo/Bhi/Blo (4 x 8KB LDS), then 48 MFMA
// (hi*hi + hi*lo + lo*hi) between one barrier pair -> 3x fewer barrier
// drains and -1/3 staging traffic vs the 3-third loop (round-6 profile:
// MfmaUtil 26%, 16 MFMA/barrier-pair).
// ---------------------------------------------------------------------------
__global__ __launch_bounds__(256) void gemm_mfma_split(
    const unsigned short* __restrict__ A,  // (M, 2K) bf16 [hi|lo]
    const unsigned short* __restrict__ B,  // (N, 2K) bf16 [hi|lo]
    const float* __restrict__ bias,        // (N,)
    float* __restrict__ C,                 // (M, N) fp32
    int M, int N, int K)                   // K = original K (512)
{
  __shared__ unsigned short Ah[128 * 32];  // 8 KB each, 32 KB total
  __shared__ unsigned short Al[128 * 32];
  __shared__ unsigned short Bh[128 * 32];
  __shared__ unsigned short Bl[128 * 32];

  const int nwg  = gridDim.x;
  const int id   = (blockIdx.x & 7) * (nwg >> 3) + (blockIdx.x >> 3);
  const int ntls = N >> 7;
  const int mt = id / ntls, nt = id % ntls;

  const int tid  = threadIdx.x;
  const int wave = tid >> 6;
  const int lane = tid & 63;
  const int wr = wave >> 1, wc = wave & 1;
  const size_t m0 = (size_t)mt * 128, n0 = (size_t)nt * 128;
  const int K2 = 2 * K;

  f32x4 acc[4][4];
#pragma unroll
  for (int i = 0; i < 4; ++i)
#pragma unroll
    for (int j = 0; j < 4; ++j) acc[i][j] = 0.f;

  const int srow = (lane >> 2);       // 0..15
  const int sko  = (lane & 3) * 8;    // bf16 elements (16B chunks)

  for (int kt = 0; kt < K; kt += 32) {
    __syncthreads();                  // prev step's readers done
#pragma unroll
    for (int L = 0; L < 2; ++L) {
      const int r0 = wave * 32 + L * 16;
      const size_t arow = (m0 + r0 + srow) * (size_t)K2;
      const size_t brow = (n0 + r0 + srow) * (size_t)K2;
      __builtin_amdgcn_global_load_lds(
          (const __attribute__((address_space(1))) unsigned int*)&A[arow + kt + sko],
          (__attribute__((address_space(3))) unsigned int*)&Ah[r0 * 32], 16, 0, 0);
      __builtin_amdgcn_global_load_lds(
          (const __attribute__((address_space(1))) unsigned int*)&A[arow + K + kt + sko],
          (__attribute__((address_space(3))) unsigned int*)&Al[r0 * 32], 16, 0, 0);
      __builtin_amdgcn_global_load_lds(
          (const __attribute__((address_space(1))) unsigned int*)&B[brow + kt + sko],
          (__attribute__((address_space(3))) unsigned int*)&Bh[r0 * 32], 16, 0, 0);
      __builtin_amdgcn_global_load_lds(
          (const __attribute__((address_space(1))) unsigned int*)&B[brow + K + kt + sko],
          (__attribute__((address_space(3))) unsigned int*)&Bl[r0 * 32], 16, 0, 0);
    }
    asm volatile("s_waitcnt vmcnt(0)" ::: "memory");
    __syncthreads();                  // all staging landed

    const int fr = lane & 15, fk = (lane >> 4) * 8;
    bf16x8 ah[4], al[4], bh[4], bl[4];
#pragma unroll
    for (int i = 0; i < 4; ++i) {
      const int ra = (wr * 64 + i * 16 + fr) * 32 + fk;
      ah[i] = *(const bf16x8*)&Ah[ra];
      al[i] = *(const bf16x8*)&Al[ra];
    }
#pragma unroll
    for (int j = 0; j < 4; ++j) {
      const int rb = (wc * 64 + j * 16 + fr) * 32 + fk;
      bh[j] = *(const bf16x8*)&Bh[rb];
      bl[j] = *(const bf16x8*)&Bl[rb];
    }
    // 48 MFMA between barrier pairs: hi*hi, hi*lo, lo*hi
#pragma unroll
    for (int i = 0; i < 4; ++i)
#pragma unroll
      for (int j = 0; j < 4; ++j)
        acc[i][j] = __builtin_amdgcn_mfma_f32_16x16x32_bf16(ah[i], bh[j], acc[i][j], 0, 0, 0);
#pragma unroll
    for (int i = 0; i < 4; ++i)
#pragma unroll
      for (int j = 0; j < 4; ++j)
        acc[i][j] = __builtin_amdgcn_mfma_f32_16x16x32_bf16(ah[i], bl[j], acc[i][j], 0, 0, 0);
#pragma unroll
    for (int i = 0; i < 4; ++i)
#pragma unroll
      for (int j = 0; j < 4; ++j)
        acc[i][j] = __builtin_amdgcn_mfma_f32_16x16x32_bf16(al[i], bh[j], acc[i][j], 0, 0, 0);
  }

  const int cr = (lane >> 4) * 4, cc = lane & 15;
#pragma unroll
  for (int j = 0; j < 4; ++j) {
    const size_t col = n0 + wc * 64 + j * 16 + cc;
    const float bv = bias[col];
#pragma unroll
    for (int i = 0; i < 4; ++i) {
      const size_t rbase = m0 + wr * 64 + i * 16 + cr;
#pragma unroll
      for (int r = 0; r < 4; ++r)
        C[(rbase + r) * (size_t)N + col] = acc[i][j][r] + bv;
    }
  }
}

// ---------------------------------------------------------------------------
// Kernel 3: MFMA cosine attention (round-6 verified structure), with the
// manual lgkmcnt(0)+sched_barrier fences REMOVED: Pql is wave-private, so
// plain LDS ops are race-free and the compiler emits counted lgkmcnt and
// pipelines across qt iterations (m97 evidence).
// ---------------------------------------------------------------------------
__global__ __launch_bounds__(256) void attn_kernel(
    const float* __restrict__ qkv,      // (CW*256, 1536)
    const float* __restrict__ table,    // (16, 961) fp32
    const float* __restrict__ lscale,   // (16,)
    const float* __restrict__ Mh,       // (16,)
    unsigned short* __restrict__ Osp)   // (CW*256, 1024) bf16 [hi|lo]
{
  __shared__ unsigned short Khi[256 * 40];   // 20 KB
  __shared__ unsigned short Klo[256 * 40];   // 20 KB
  __shared__ unsigned short Vth[32 * 264];   // 16.5 KB
  __shared__ unsigned short Pql[4 * 512];    // 4 KB (1 KB per wave, wave-private)
  __shared__ unsigned short btb[962];        // 1.9 KB bias (bf16)

  const int b = blockIdx.x, h = blockIdx.y, t = threadIdx.x;
  const int lane = t & 63, w = t >> 6;
  const int G = lane >> 4, ql = lane & 15;
  const float scale = __expf(fminf(lscale[h], LOG_MAX_F));
  const float Mhv = Mh[h];

  // ---- stage K row t: L2-normalize, hi/lo split ----
  {
    const size_t rb = ((size_t)(b*LTOK + t)) * (3*CCH) + CCH + h*DH;
    float4 kr[8]; float nk = 0.f;
#pragma unroll
    for (int c = 0; c < 8; ++c) {
      kr[c] = *(const float4*)&qkv[rb + c*4];
      nk += kr[c].x*kr[c].x + kr[c].y*kr[c].y + kr[c].z*kr[c].z + kr[c].w*kr[c].w;
    }
    const float ik = 1.f / fmaxf(sqrtf(nk), EPS_F);
#pragma unroll
    for (int c = 0; c < 4; ++c) {
      float f[8] = {kr[2*c].x*ik, kr[2*c].y*ik, kr[2*c].z*ik, kr[2*c].w*ik,
                    kr[2*c+1].x*ik, kr[2*c+1].y*ik, kr[2*c+1].z*ik, kr[2*c+1].w*ik};
      bf16x8 hi, lo;
#pragma unroll
      for (int j = 0; j < 8; ++j) {
        unsigned int u = __float_as_uint(f[j]);
        hi[j] = (short)(u >> 16);
        lo[j] = (short)bf16rne(f[j] - __uint_as_float(u & 0xffff0000u));
      }
      *(bf16x8*)&Khi[t*40 + c*8] = hi;
      *(bf16x8*)&Klo[t*40 + c*8] = lo;
    }
  }
  // ---- stage V row t: bf16-RNE, transposed [d][key] ----
  {
    const size_t rb = ((size_t)(b*LTOK + t)) * (3*CCH) + 2*CCH + h*DH;
#pragma unroll
    for (int c = 0; c < 8; ++c) {
      float4 v = *(const float4*)&qkv[rb + c*4];
      Vth[(4*c+0)*264 + t] = bf16rne(v.x);
      Vth[(4*c+1)*264 + t] = bf16rne(v.y);
      Vth[(4*c+2)*264 + t] = bf16rne(v.z);
      Vth[(4*c+3)*264 + t] = bf16rne(v.w);
    }
  }
  // ---- stage bias (bf16) ----
  for (int e = t; e < 961; e += 256) btb[e] = bf16rne(table[h*961 + e]);

  // ---- Q fragments in registers: [qt] hi/lo, scale & 1/norm folded ----
  bf16x8 Qh[4], Qlr[4];
#pragma unroll
  for (int qt = 0; qt < 4; ++qt) {
    const int qrow = b*LTOK + w*64 + qt*16 + ql;
    const float* qp = &qkv[(size_t)qrow * (3*CCH) + h*DH + G*8];
    float4 a = *(const float4*)qp;
    float4 b4 = *(const float4*)(qp + 4);
    float ss = a.x*a.x + a.y*a.y + a.z*a.z + a.w*a.w
             + b4.x*b4.x + b4.y*b4.y + b4.z*b4.z + b4.w*b4.w;
    ss += __shfl_xor(ss, 16);
    ss += __shfl_xor(ss, 32);
    const float iq = scale / fmaxf(sqrtf(ss), EPS_F);
    float f[8] = {a.x*iq, a.y*iq, a.z*iq, a.w*iq, b4.x*iq, b4.y*iq, b4.z*iq, b4.w*iq};
#pragma unroll
    for (int j = 0; j < 8; ++j) {
      unsigned int u = __float_as_uint(f[j]);
      Qh[qt][j]  = (short)(u >> 16);
      Qlr[qt][j] = (short)bf16rne(f[j] - __uint_as_float(u & 0xffff0000u));
    }
  }
  __syncthreads();

  f32x4 accO[2][4];
#pragma unroll
  for (int i = 0; i < 2; ++i)
#pragma unroll
    for (int j = 0; j < 4; ++j) accO[i][j] = 0.f;
  float lsum[4] = {0.f, 0.f, 0.f, 0.f};

  const int pbase = w * 512;   // wave-private P region (ushort units)

  for (int kp = 0; kp < 8; ++kp) {
    bf16x8 kh[2], kl[2], vf[2];
#pragma unroll
    for (int tt = 0; tt < 2; ++tt) {
      const int krow = kp*32 + tt*16 + ql;
      kh[tt] = *(const bf16x8*)&Khi[krow*40 + G*8];
      kl[tt] = *(const bf16x8*)&Klo[krow*40 + G*8];
    }
#pragma unroll
    for (int dt = 0; dt < 2; ++dt)
      vf[dt] = *(const bf16x8*)&Vth[(dt*16 + ql)*264 + kp*32 + G*8];

#pragma unroll
    for (int qt = 0; qt < 4; ++qt) {
      // --- S^T tiles: 3-product split, D[key_in_tile, q] ---
      f32x4 st0, st1; st0 = 0.f; st1 = 0.f;
      st0 = __builtin_amdgcn_mfma_f32_16x16x32_bf16(kl[0], Qh[qt],  st0, 0,0,0);
      st0 = __builtin_amdgcn_mfma_f32_16x16x32_bf16(kh[0], Qlr[qt], st0, 0,0,0);
      st0 = __builtin_amdgcn_mfma_f32_16x16x32_bf16(kh[0], Qh[qt],  st0, 0,0,0);
      st1 = __builtin_amdgcn_mfma_f32_16x16x32_bf16(kl[1], Qh[qt],  st1, 0,0,0);
      st1 = __builtin_amdgcn_mfma_f32_16x16x32_bf16(kh[1], Qlr[qt], st1, 0,0,0);
      st1 = __builtin_amdgcn_mfma_f32_16x16x32_bf16(kh[1], Qh[qt],  st1, 0,0,0);

      // --- bias + bound-softmax + bf16 pack ---
      const int qg = w*64 + qt*16 + ql;
      const int qi = qg >> 4, qj = qg & 15;
      unsigned short ph[2][4];
#pragma unroll
      for (int tt = 0; tt < 2; ++tt) {
        const int ki = kp*2 + tt;
#pragma unroll
        for (int r = 0; r < 4; ++r) {
          const int kj = 4*G + r;
          const float bv = bf2f(btb[(qi - ki + 15)*31 + (qj - kj + 15)]);
          const float sv = (tt == 0) ? st0[r] : st1[r];
          const float p = __expf(sv + bv - Mhv);
          const unsigned short us = bf16rne(p);
          ph[tt][r] = us;
          lsum[qt] += bf2f(us);          // sum the SAME rounded p used in PV
        }
      }

      // wave-private LDS bounce; compiler inserts counted lgkmcnt
#pragma unroll
      for (int tt = 0; tt < 2; ++tt) {
        const int chunkw = 2*tt + (G >> 1);
        const int widx = pbase + ql*32 + ((chunkw ^ (ql & 3)) * 8) + (G & 1)*4;
        *(ushort4*)&Pql[widx] = make_ushort4(ph[tt][0], ph[tt][1], ph[tt][2], ph[tt][3]);
      }
      const bf16x8 pb = *(const bf16x8*)&Pql[pbase + ql*32 + ((G ^ (ql & 3)) * 8)];
      accO[0][qt] = __builtin_amdgcn_mfma_f32_16x16x32_bf16(vf[0], pb, accO[0][qt], 0,0,0);
      accO[1][qt] = __builtin_amdgcn_mfma_f32_16x16x32_bf16(vf[1], pb, accO[1][qt], 0,0,0);
    }
  }

  // ---- epilogue: 1/l, split-write O ----
#pragma unroll
  for (int qt = 0; qt < 4; ++qt) {
    float lq = lsum[qt];
    lq += __shfl_xor(lq, 16);
    lq += __shfl_xor(lq, 32);
    const float inv = 1.f / fmaxf(lq, 1e-37f);
    const int qrow = b*LTOK + w*64 + qt*16 + ql;
#pragma unroll
    for (int dt = 0; dt < 2; ++dt) {
      unsigned short hv[4], lv[4];
#pragma unroll
      for (int r = 0; r < 4; ++r) {
        const float v = accO[dt][qt][r] * inv;
        const unsigned int u = __float_as_uint(v);
        hv[r] = (unsigned short)(u >> 16);
        lv[r] = bf16rne(v - __uint_as_float(u & 0xffff0000u));
      }
      unsigned short* ob = &Osp[(size_t)qrow * 1024 + h*DH + dt*16 + G*4];
      *(ushort4*)ob         = make_ushort4(hv[0], hv[1], hv[2], hv[3]);
      *(ushort4*)(ob + 512) = make_ushort4(lv[0], lv[1], lv[2], lv[3]);
    }
  }
}

// ---------------------------------------------------------------------------
// Driver (unchanged from round 6).
// ---------------------------------------------------------------------------
extern "C" void kernel_launch(void* const* d_in, const int* in_sizes, int n_in,
                              void* d_out, int out_size, void* d_ws, size_t ws_size,
                              hipStream_t stream) {
  const float* x      = (const float*)d_in[0];
  const float* qkv_w  = (const float*)d_in[1];
  const float* qkv_b  = (const float*)d_in[2];
  const float* proj_w = (const float*)d_in[3];
  const float* proj_b = (const float*)d_in[4];
  const float* fc1_w  = (const float*)d_in[5];
  const float* fc1_b  = (const float*)d_in[6];
  const float* fc2_w  = (const float*)d_in[7];
  const float* fc2_b  = (const float*)d_in[8];
  const float* ls     = (const float*)d_in[9];
  float* out = (float*)d_out;

  const size_t FIXED   = 65536 + (size_t)1536*1024*2 + (size_t)512*1024*2;
  const size_t PER_WIN = (size_t)LTOK*(3*CCH)*4 + 2*(size_t)LTOK*1024*2; // 2.5 MiB

  int CW = NBW;
  while (CW > 4 && FIXED + (size_t)CW * PER_WIN > ws_size) CW >>= 1;

  char* p = (char*)d_ws;
  float*          table   = (float*)p;          p += 65536;
  unsigned short* qkvw_s  = (unsigned short*)p; p += (size_t)1536*1024*2;
  unsigned short* projw_s = (unsigned short*)p; p += (size_t)512*1024*2;
  float*          qkvbuf  = (float*)p;          p += (size_t)CW*LTOK*(3*CCH)*4;
  unsigned short* xsplit  = (unsigned short*)p; p += (size_t)CW*LTOK*1024*2;
  unsigned short* osplit  = (unsigned short*)p;
  float*          MhPtr   = table + NH*961;     // inside the 64KB table region

  // bias table + M_h + weight splits (once per call)
  bias_mlp_kernel<<<dim3(961), dim3(64), 0, stream>>>(fc1_w, fc1_b, fc2_w, fc2_b, table);
  mh_kernel<<<dim3(1), dim3(256), 0, stream>>>(table, ls, MhPtr);
  split_kernel<<<dim3(768), dim3(256), 0, stream>>>(qkv_w, qkvw_s, (long)1536*512);
  split_kernel<<<dim3(256), dim3(256), 0, stream>>>(proj_w, projw_s, (long)512*512);

  const int Mc = CW * LTOK;
  const long xElems = (long)Mc * CCH;
  const int splitGrid = (int)((xElems/4 + 255) / 256) > 2048 ? 2048
                        : (int)((xElems/4 + 255) / 256);

  for (int c0 = 0; c0 < NBW; c0 += CW) {
    const float* xc = x   + (size_t)c0 * LTOK * CCH;
    float*       oc = out + (size_t)c0 * LTOK * CCH;

    // split x chunk -> [hi|lo] bf16
    split_kernel<<<dim3(splitGrid), dim3(256), 0, stream>>>(xc, xsplit, xElems);

    // QKV projection: (Mc,512) @ (1536,512)^T + bias, split-bf16 MFMA
    gemm_mfma_split<<<dim3((Mc/128) * (1536/128)), dim3(256), 0, stream>>>(
        xsplit, qkvw_s, qkv_b, qkvbuf, Mc, 1536, CCH);

    // MFMA attention per (window-in-chunk, head); writes O in split form
    attn_kernel<<<dim3(CW, NH), dim3(256), 0, stream>>>(
        qkvbuf, table, ls, MhPtr, osplit);

    // output projection: (Mc,512) @ (512,512)^T + bias
    gemm_mfma_split<<<dim3((Mc/128) * (512/128)), dim3(256), 0, stream>>>(
        osplit, projw_s, proj_b, oc, Mc, 512, CCH);
  }
}